// Round 14
// baseline (88.154 us; speedup 1.0000x reference)
//
#include <hip/hip_runtime.h>
#include <hip/hip_fp16.h>

#define NN 1536      // n_nodes
#define FDIM 32      // p == fts == 32
#define TG 96        // tile (grid 16x16 = 256 blocks = 1/CU, 8 waves each)
#define KS 32        // K-step per half (64 B per row)
#define NTH 24       // K-steps per half (768/32)

typedef __attribute__((ext_vector_type(8))) __bf16 bf16x8;
typedef __attribute__((ext_vector_type(4))) float f32x4;
typedef _Float16 h16x2 __attribute__((ext_vector_type(2)));

typedef __attribute__((address_space(3))) unsigned char as3_u8;
typedef __attribute__((address_space(1))) unsigned char as1_u8;

__device__ __forceinline__ void gload_lds16(const void* g, void* l) {
    __builtin_amdgcn_global_load_lds((const as1_u8*)g, (as3_u8*)l, 16, 0, 0);
}

__device__ __forceinline__ unsigned short bf16rne(float f) {
    unsigned u = __float_as_uint(f);
    return (unsigned short)((u + 0x7FFFu + ((u >> 16) & 1u)) >> 16);
}

// ---------------------------------------------------------------------------
// Fused split (A -> bf16 hi/lo) + prep (Q_l = P @ W1[l], f16 QI/RJ).
// ---------------------------------------------------------------------------
__global__ __launch_bounds__(256) void gud_splitprep(
        const float* __restrict__ A,
        unsigned short* __restrict__ Ah,
        unsigned short* __restrict__ Al,
        const float* __restrict__ P,
        const float* __restrict__ W1,
        const float* __restrict__ b1,
        _Float16* __restrict__ QIh,
        _Float16* __restrict__ RJh) {
    const int b = blockIdx.x;
    if (b < NN * NN / 1024) {
        int gid = b * 256 + threadIdx.x;           // 4 floats per thread
        float4 v = reinterpret_cast<const float4*>(A)[gid];
        ushort4 h, l;
        float x;
        x = v.x; h.x = bf16rne(x); l.x = bf16rne(x - __uint_as_float((unsigned)h.x << 16));
        x = v.y; h.y = bf16rne(x); l.y = bf16rne(x - __uint_as_float((unsigned)h.y << 16));
        x = v.z; h.z = bf16rne(x); l.z = bf16rne(x - __uint_as_float((unsigned)h.z << 16));
        x = v.w; h.w = bf16rne(x); l.w = bf16rne(x - __uint_as_float((unsigned)h.w << 16));
        reinterpret_cast<ushort4*>(Ah)[gid] = h;
        reinterpret_cast<ushort4*>(Al)[gid] = l;
    } else {
        int gid = (b - NN * NN / 1024) * 256 + threadIdx.x;   // 0 .. NN*64-1
        int i  = gid >> 6;
        int lf = gid & 63;
        int l  = (lf >> 5) + 1;   // 1 or 2
        int f  = lf & 31;
        const float* prow = P + i * FDIM;
        const float* wp   = W1 + l * FDIM * FDIM + f;
        float q = 0.f;
#pragma unroll
        for (int c = 0; c < FDIM; ++c) q = fmaf(prow[c], wp[c * FDIM], q);
        QIh[i * 64 + lf] = (_Float16)(q + b1[l * FDIM + f]);
        RJh[i * 64 + lf] = (_Float16)(-q);
    }
}

// ---------------------------------------------------------------------------
// Fused GEMM + conv, REGISTER-STREAMING: no LDS staging, no K-loop barriers.
// 8 waves = (kh, wr, wc); each wave loads its 12 MFMA fragments per K-step
// straight from global (L1/L2-served, 64B-sector clean) into 3 rotating
// register sets (2-step lookahead hides L2 latency), fully per-wave async.
// LDS only for acc exchange + QI/RJ epilogue tiles (61440 B).
// ---------------------------------------------------------------------------
__global__ __launch_bounds__(512, 1) void gud_fused(
        const unsigned short* __restrict__ Ah,
        const unsigned short* __restrict__ Al,
        const float* __restrict__ A,
        const _Float16* __restrict__ QIh,
        const _Float16* __restrict__ RJh,
        const float* __restrict__ b1,
        const float* __restrict__ W2,
        const float* __restrict__ b2,
        float* __restrict__ out) {
    __shared__ char smem[61440];   // QI 12288 | RJ 12288 | acc-exch 4*9216

    const int tid  = threadIdx.x;
    const int lane = tid & 63;
    const int w    = tid >> 6;          // wave 0..7
    const int kh   = w >> 2;            // K-half
    const int sub  = w & 3;
    const int wr   = sub >> 1, wc = sub & 1;

    // XCD-chunked swizzle over the 256-block grid (256 % 8 == 0)
    const int lin = blockIdx.x;
    const int swz = (lin & 7) * 32 + (lin >> 3);
    const int by  = swz >> 4, bx = swz & 15;
    const int i0  = by * TG, j0 = bx * TG;

    // ---- per-lane fragment offsets (ushort units); advance kt*32 per K-step
    int offA[3], offB[3];
#pragma unroll
    for (int m = 0; m < 3; ++m) {
        offA[m] = (i0 + wr * 48 + m * 16 + (lane & 15)) * NN + kh * (NN / 2) + (lane >> 4) * 8;
        offB[m] = (j0 + wc * 48 + m * 16 + (lane & 15)) * NN + kh * (NN / 2) + (lane >> 4) * 8;
    }

    f32x4 acc[3][3];
#pragma unroll
    for (int m = 0; m < 3; ++m)
#pragma unroll
        for (int n = 0; n < 3; ++n) acc[m][n] = (f32x4){0.f, 0.f, 0.f, 0.f};

    // operand register sets: [0..2]=Ah frags, [3..5]=Al, [6..8]=Bh, [9..11]=Bl
    bf16x8 s0[12], s1[12], s2[12];

#define LOADSET(S, KT) do {                                                  \
    const int o_ = (KT) * 32;                                                \
    S[0]  = *(const bf16x8*)(Ah + offA[0] + o_);                             \
    S[1]  = *(const bf16x8*)(Ah + offA[1] + o_);                             \
    S[2]  = *(const bf16x8*)(Ah + offA[2] + o_);                             \
    S[3]  = *(const bf16x8*)(Al + offA[0] + o_);                             \
    S[4]  = *(const bf16x8*)(Al + offA[1] + o_);                             \
    S[5]  = *(const bf16x8*)(Al + offA[2] + o_);                             \
    S[6]  = *(const bf16x8*)(Ah + offB[0] + o_);                             \
    S[7]  = *(const bf16x8*)(Ah + offB[1] + o_);                             \
    S[8]  = *(const bf16x8*)(Ah + offB[2] + o_);                             \
    S[9]  = *(const bf16x8*)(Al + offB[0] + o_);                             \
    S[10] = *(const bf16x8*)(Al + offB[1] + o_);                             \
    S[11] = *(const bf16x8*)(Al + offB[2] + o_);                             \
} while (0)

#define MFMASET(S) do {                                                      \
    _Pragma("unroll")                                                        \
    for (int m = 0; m < 3; ++m)                                              \
        _Pragma("unroll")                                                    \
        for (int n = 0; n < 3; ++n) {                                        \
            acc[m][n] = __builtin_amdgcn_mfma_f32_16x16x32_bf16(S[m],     S[6 + n], acc[m][n], 0, 0, 0); \
            acc[m][n] = __builtin_amdgcn_mfma_f32_16x16x32_bf16(S[3 + m], S[6 + n], acc[m][n], 0, 0, 0); \
            acc[m][n] = __builtin_amdgcn_mfma_f32_16x16x32_bf16(S[m],     S[9 + n], acc[m][n], 0, 0, 0); \
        }                                                                    \
} while (0)

    // ---- 3-deep pipeline, no barriers: per-wave vmcnt only
    LOADSET(s0, 0);
    LOADSET(s1, 1);
    LOADSET(s2, 2);
#pragma unroll 2
    for (int kt = 0; kt < NTH; kt += 3) {
        MFMASET(s0);
        if (kt + 3 < NTH) LOADSET(s0, kt + 3);
        MFMASET(s1);
        if (kt + 4 < NTH) LOADSET(s1, kt + 4);
        MFMASET(s2);
        if (kt + 5 < NTH) LOADSET(s2, kt + 5);
    }

    // ---- acc exchange (kh=1 -> LDS) + QI/RJ staging
    if (kh == 1) {
        char* pbase = smem + 24576 + sub * 9216 + lane * 144;
#pragma unroll
        for (int m = 0; m < 3; ++m)
#pragma unroll
            for (int n = 0; n < 3; ++n)
                *(f32x4*)(pbase + (m * 3 + n) * 16) = acc[m][n];
    }
    if (w < 4) {        // QI: 96 rows x 128 B -> smem[0..12288)
#pragma unroll
        for (int sl = 0; sl < 3; ++sl) {
            int base = (w * 3 + sl) * 64;
            int idx  = base + lane;
            int c    = idx / 96;
            int row  = idx - c * 96;
            gload_lds16(QIh + (size_t)(i0 + row) * 64 + c * 8, smem + base * 16);
        }
    } else {            // RJ -> smem[12288..24576)
#pragma unroll
        for (int sl = 0; sl < 3; ++sl) {
            int base = ((w - 4) * 3 + sl) * 64;
            int idx  = base + lane;
            int c    = idx / 96;
            int row  = idx - c * 96;
            gload_lds16(RJh + (size_t)(j0 + row) * 64 + c * 8, smem + 12288 + base * 16);
        }
    }

    // epilogue geometry + early A loads (kh=0 only)
    const int crow = (lane >> 4) * 4;
    const int ccol = lane & 15;
    int il[3], jl[3];
#pragma unroll
    for (int m = 0; m < 3; ++m) il[m] = wr * 48 + m * 16 + crow;
#pragma unroll
    for (int n = 0; n < 3; ++n) jl[n] = wc * 48 + n * 16 + ccol;

    float av[3][3][4];
    if (kh == 0) {
#pragma unroll
        for (int m = 0; m < 3; ++m)
#pragma unroll
            for (int n = 0; n < 3; ++n)
#pragma unroll
                for (int r = 0; r < 4; ++r)
                    av[m][n][r] = A[(size_t)(i0 + il[m] + r) * NN + j0 + jl[n]];
    }

    __syncthreads();    // drains vmcnt (QI/RJ, A) + lgkm (acc ds_writes)

    if (kh == 1) return;

    // ---- add partner half's accumulators
    {
        const char* pbase = smem + 24576 + sub * 9216 + lane * 144;
#pragma unroll
        for (int m = 0; m < 3; ++m)
#pragma unroll
            for (int n = 0; n < 3; ++n)
                acc[m][n] += *(const f32x4*)(pbase + (m * 3 + n) * 16);
    }

    // ---- conv epilogue (f16 dot2, two-pass; r7/r13-verified)
    const char* QIl = smem;
    const char* RJl = smem + 12288;

    float c0 = b2[0];
#pragma unroll
    for (int f = 0; f < FDIM; ++f) c0 = fmaf(fmaxf(b1[f], 0.f), W2[f], c0);
    const float bb1 = b2[1], bb2 = b2[2];

    h16x2 w2h[32];
#pragma unroll
    for (int k = 0; k < 32; ++k) {
        h16x2 t; t.x = (_Float16)W2[32 + 2 * k]; t.y = (_Float16)W2[33 + 2 * k];
        w2h[k] = t;
    }

    float mm[3][3][4];
    // pass 1: chunks 0..3 (features 0..31, layer 1) -> m1, fold into av
#pragma unroll
    for (int m = 0; m < 3; ++m)
#pragma unroll
        for (int n = 0; n < 3; ++n)
#pragma unroll
            for (int r = 0; r < 4; ++r) mm[m][n][r] = 0.f;
#pragma unroll
    for (int c = 0; c < 4; ++c) {
        uint4 rv[3];
#pragma unroll
        for (int n = 0; n < 3; ++n)
            rv[n] = *(const uint4*)(RJl + (c * 96 + jl[n]) * 16);
        uint4 qv[3][4];
#pragma unroll
        for (int m = 0; m < 3; ++m)
#pragma unroll
            for (int r = 0; r < 4; ++r)
                qv[m][r] = *(const uint4*)(QIl + (c * 96 + il[m] + r) * 16);
#pragma unroll
        for (int m = 0; m < 3; ++m)
#pragma unroll
            for (int n = 0; n < 3; ++n) {
                const unsigned* ru = (const unsigned*)&rv[n];
#pragma unroll
                for (int r = 0; r < 4; ++r) {
                    const unsigned* qu = (const unsigned*)&qv[m][r];
                    float acc_f = mm[m][n][r];
#pragma unroll
                    for (int e = 0; e < 4; ++e) {
                        h16x2 q = __builtin_bit_cast(h16x2, qu[e]);
                        h16x2 j = __builtin_bit_cast(h16x2, ru[e]);
                        h16x2 h = q + j;
                        h16x2 z = {(_Float16)0, (_Float16)0};
                        h = __builtin_elementwise_max(h, z);
                        acc_f = __builtin_amdgcn_fdot2(h, w2h[c * 4 + e], acc_f, false);
                    }
                    mm[m][n][r] = acc_f;
                }
            }
    }
#pragma unroll
    for (int m = 0; m < 3; ++m)
#pragma unroll
        for (int n = 0; n < 3; ++n)
#pragma unroll
            for (int r = 0; r < 4; ++r)
                av[m][n][r] *= (mm[m][n][r] + bb1);

    // pass 2: chunks 4..7 (features 32..63, layer 2) -> m2
#pragma unroll
    for (int m = 0; m < 3; ++m)
#pragma unroll
        for (int n = 0; n < 3; ++n)
#pragma unroll
            for (int r = 0; r < 4; ++r) mm[m][n][r] = 0.f;
#pragma unroll
    for (int c = 4; c < 8; ++c) {
        uint4 rv[3];
#pragma unroll
        for (int n = 0; n < 3; ++n)
            rv[n] = *(const uint4*)(RJl + (c * 96 + jl[n]) * 16);
        uint4 qv[3][4];
#pragma unroll
        for (int m = 0; m < 3; ++m)
#pragma unroll
            for (int r = 0; r < 4; ++r)
                qv[m][r] = *(const uint4*)(QIl + (c * 96 + il[m] + r) * 16);
#pragma unroll
        for (int m = 0; m < 3; ++m)
#pragma unroll
            for (int n = 0; n < 3; ++n) {
                const unsigned* ru = (const unsigned*)&rv[n];
#pragma unroll
                for (int r = 0; r < 4; ++r) {
                    const unsigned* qu = (const unsigned*)&qv[m][r];
                    float acc_f = mm[m][n][r];
#pragma unroll
                    for (int e = 0; e < 4; ++e) {
                        h16x2 q = __builtin_bit_cast(h16x2, qu[e]);
                        h16x2 j = __builtin_bit_cast(h16x2, ru[e]);
                        h16x2 h = q + j;
                        h16x2 z = {(_Float16)0, (_Float16)0};
                        h = __builtin_elementwise_max(h, z);
                        acc_f = __builtin_amdgcn_fdot2(h, w2h[c * 4 + e], acc_f, false);
                    }
                    mm[m][n][r] = acc_f;
                }
            }
    }

    // final: out = A*(m1+bb1) + A2*(m2+bb2) + diag(c0)
#pragma unroll
    for (int m = 0; m < 3; ++m)
#pragma unroll
        for (int n = 0; n < 3; ++n)
#pragma unroll
            for (int r = 0; r < 4; ++r) {
                float v = av[m][n][r] + acc[m][n][r] * (mm[m][n][r] + bb2);
                int gi = i0 + il[m] + r;
                int gj = j0 + jl[n];
                if (gi == gj) v += c0;
                out[(size_t)gi * NN + gj] = v;
            }
}

// ---------------------------------------------------------------------------
extern "C" void kernel_launch(void* const* d_in, const int* in_sizes, int n_in,
                              void* d_out, int out_size, void* d_ws, size_t ws_size,
                              hipStream_t stream) {
    const float* A  = (const float*)d_in[0];   // [NN,NN] A_norm (symmetric)
    const float* P  = (const float*)d_in[1];   // [NN,32]
    const float* W1 = (const float*)d_in[2];   // [3,32,32]
    const float* b1 = (const float*)d_in[3];   // [3,32]
    const float* W2 = (const float*)d_in[4];   // [3,32,1]
    const float* b2 = (const float*)d_in[5];   // [3,1]
    float* out = (float*)d_out;

    unsigned short* Ahh = (unsigned short*)d_ws;                 // NN*NN bf16
    unsigned short* All = Ahh + (size_t)NN * NN;                 // NN*NN bf16
    _Float16* QIh = (_Float16*)(All + (size_t)NN * NN);          // NN*64 f16
    _Float16* RJh = QIh + (size_t)NN * 64;                       // NN*64 f16

    gud_splitprep<<<dim3(NN * NN / 1024 + NN * 64 / 256), 256, 0, stream>>>(
        A, Ahh, All, P, W1, b1, QIh, RJh);
    gud_fused<<<dim3((NN / TG) * (NN / TG)), 512, 0, stream>>>(
        Ahh, All, A, QIh, RJh, b1, W2, b2, out);
}

// Round 15
// 47.074 us; speedup vs baseline: 1.8727x; 1.8727x over previous
//
#include <hip/hip_runtime.h>
#include <hip/hip_fp16.h>

#define NN 1536      // n_nodes
#define FDIM 32      // p == fts == 32
#define TG 96        // tile (grid 16x16 = 256 blocks = 1/CU, 8 waves each)
#define KS 64        // i8 K-step per half (64 B per row)
#define NTH 12       // K-steps per half (768/64)

typedef __attribute__((ext_vector_type(4))) int i32x4;
typedef __attribute__((ext_vector_type(4))) float f32x4;
typedef _Float16 h16x2 __attribute__((ext_vector_type(2)));

typedef __attribute__((address_space(3))) unsigned char as3_u8;
typedef __attribute__((address_space(1))) unsigned char as1_u8;

__device__ __forceinline__ void gload_lds16(const void* g, void* l) {
    __builtin_amdgcn_global_load_lds((const as1_u8*)g, (as3_u8*)l, 16, 0, 0);
}

// ---------------------------------------------------------------------------
// absmax(A): 256 blocks grid-stride, wave shuffle-reduce, LDS cross-wave,
// ONE atomic per block (r6-verified; r5's 9216 same-address atomics = 107us).
// ---------------------------------------------------------------------------
__global__ __launch_bounds__(256) void gud_absmax(const float* __restrict__ A,
                                                  unsigned* __restrict__ amax) {
    __shared__ float red[4];
    const float4* A4 = reinterpret_cast<const float4*>(A);
    float m = 0.f;
    for (int idx = blockIdx.x * 256 + threadIdx.x; idx < NN * NN / 4;
         idx += 256 * 256) {
        float4 v = A4[idx];
        m = fmaxf(m, fmaxf(fmaxf(fabsf(v.x), fabsf(v.y)),
                           fmaxf(fabsf(v.z), fabsf(v.w))));
    }
#pragma unroll
    for (int k = 32; k >= 1; k >>= 1)
        m = fmaxf(m, __shfl_xor(m, k, 64));
    if ((threadIdx.x & 63) == 0) red[threadIdx.x >> 6] = m;
    __syncthreads();
    if (threadIdx.x == 0) {
        m = fmaxf(fmaxf(red[0], red[1]), fmaxf(red[2], red[3]));
        atomicMax(amax, __float_as_uint(m));
    }
}

// ---------------------------------------------------------------------------
// Fused quant (A -> i8 H/L, 15-bit fixed point, r6-verified) + prep
// (Q_l = P @ W1[l], f16 QI/RJ). Blocks [0,2304): quant; [2304,2688): prep.
// ---------------------------------------------------------------------------
__global__ __launch_bounds__(256) void gud_quantprep(
        const float* __restrict__ A,
        const unsigned* __restrict__ amaxu,
        unsigned char* __restrict__ qH,
        unsigned char* __restrict__ qL,
        const float* __restrict__ P,
        const float* __restrict__ W1,
        const float* __restrict__ b1,
        _Float16* __restrict__ QIh,
        _Float16* __restrict__ RJh) {
    const int b = blockIdx.x;
    if (b < NN * NN / 1024) {
        const float inv = 32639.0f / __uint_as_float(*amaxu);
        int gid = b * 256 + threadIdx.x;
        float4 v = reinterpret_cast<const float4*>(A)[gid];
        unsigned hw = 0, lw = 0;
        float elems[4] = {v.x, v.y, v.z, v.w};
#pragma unroll
        for (int e = 0; e < 4; ++e) {
            int q  = (int)rintf(fminf(fmaxf(elems[e] * inv, -32639.f), 32639.f));
            int hh = (q + 128) >> 8;           // floor((q+128)/256)
            int ll = q - (hh << 8);            // in [-128,127]
            hw |= ((unsigned)(hh & 0xff)) << (8 * e);
            lw |= ((unsigned)(ll & 0xff)) << (8 * e);
        }
        reinterpret_cast<unsigned*>(qH)[gid] = hw;
        reinterpret_cast<unsigned*>(qL)[gid] = lw;
    } else {
        int gid = (b - NN * NN / 1024) * 256 + threadIdx.x;   // 0 .. NN*64-1
        int i  = gid >> 6;
        int lf = gid & 63;
        int l  = (lf >> 5) + 1;   // 1 or 2
        int f  = lf & 31;
        const float* prow = P + i * FDIM;
        const float* wp   = W1 + l * FDIM * FDIM + f;
        float q = 0.f;
#pragma unroll
        for (int c = 0; c < FDIM; ++c) q = fmaf(prow[c], wp[c * FDIM], q);
        QIh[i * 64 + lf] = (_Float16)(q + b1[l * FDIM + f]);
        RJh[i * 64 + lf] = (_Float16)(-q);
    }
}

// ---------------------------------------------------------------------------
// Fused i8 GEMM + conv (r13 structure, i8 numerics). 8 waves = (kh, wr, wc):
// K split across waves; each wave runs the 3-buf / 2-deep / vmcnt(6) pipeline
// over its 768-wide K-half with K=64 steps (12 barriers vs r13's 24, half the
// MFMA instructions, half the staged bytes). A2 = s^2(65536 HH + 256(HL+LH));
// kh=1 a2 exchanged via LDS; kh=0 waves run the f16 conv epilogue.
// ---------------------------------------------------------------------------
__global__ __launch_bounds__(512, 1) void gud_fused(
        const unsigned char* __restrict__ qH,
        const unsigned char* __restrict__ qL,
        const unsigned* __restrict__ amaxu,
        const float* __restrict__ A,
        const _Float16* __restrict__ QIh,
        const _Float16* __restrict__ RJh,
        const float* __restrict__ b1,
        const float* __restrict__ W2,
        const float* __restrict__ b2,
        float* __restrict__ out) {
    // 3 buffers x (2 halves x 4 subtiles x 96 rows x 64 B) = 3 x 49152
    __shared__ char smem[3 * 49152];

    const int tid  = threadIdx.x;
    const int lane = tid & 63;
    const int w    = tid >> 6;          // wave 0..7
    const int kh   = w >> 2;            // K-half
    const int sub  = w & 3;             // 0=H@i0, 1=L@i0, 2=H@j0, 3=L@j0
    const int wr   = sub >> 1, wc = sub & 1;

    // XCD-chunked swizzle over the 256-block grid (256 % 8 == 0)
    const int lin = blockIdx.x;
    const int swz = (lin & 7) * 32 + (lin >> 3);
    const int by  = swz >> 4, bx = swz & 15;
    const int i0  = by * TG, j0 = bx * TG;

    // ---- staging: wave w owns subtile (kh, sub) of each buffer
    const unsigned char* src = (sub & 1) ? qL : qH;
    const int rowbase = (sub < 2) ? i0 : j0;
    const int khbyte  = kh * (NN / 2);  // kh * 768 cols * 1 B
    int goffs[6];
#pragma unroll
    for (int s = 0; s < 6; ++s) {
        int rt    = 16 * s + (lane >> 2);          // row within tile 0..95
        int chunk = (lane & 3) ^ ((rt >> 1) & 3);  // inverse swizzle on source
        goffs[s]  = (rowbase + rt) * NN + khbyte + chunk * 16;
    }

    // ---- fragment read offsets (within this half's region of a buffer)
    const int hbase = kh * 24576;
    int aoff[3], boff[3];
    const int kb = lane >> 4;
#pragma unroll
    for (int m = 0; m < 3; ++m) {
        int ra  = wr * 48 + m * 16 + (lane & 15);
        aoff[m] = hbase + ra * 64 + ((kb ^ ((ra >> 1) & 3)) * 16);
        int rb  = wc * 48 + m * 16 + (lane & 15);
        boff[m] = hbase + 12288 + rb * 64 + ((kb ^ ((rb >> 1) & 3)) * 16);
    }

    i32x4 accH[3][3], accX[3][3];
#pragma unroll
    for (int m = 0; m < 3; ++m)
#pragma unroll
        for (int n = 0; n < 3; ++n) {
            accH[m][n] = (i32x4){0, 0, 0, 0};
            accX[m][n] = (i32x4){0, 0, 0, 0};
        }

    auto compute = [&](const char* buf) {
        i32x4 hA[3], lA[3], hB[3], lB[3];
#pragma unroll
        for (int m = 0; m < 3; ++m) {
            hA[m] = *(const i32x4*)(buf + aoff[m]);
            lA[m] = *(const i32x4*)(buf + aoff[m] + 6144);
            hB[m] = *(const i32x4*)(buf + boff[m]);
            lB[m] = *(const i32x4*)(buf + boff[m] + 6144);
        }
#pragma unroll
        for (int m = 0; m < 3; ++m)
#pragma unroll
            for (int n = 0; n < 3; ++n) {
                accH[m][n] = __builtin_amdgcn_mfma_i32_16x16x64_i8(hA[m], hB[n], accH[m][n], 0, 0, 0);
                accX[m][n] = __builtin_amdgcn_mfma_i32_16x16x64_i8(hA[m], lB[n], accX[m][n], 0, 0, 0);
                accX[m][n] = __builtin_amdgcn_mfma_i32_16x16x64_i8(lA[m], hB[n], accX[m][n], 0, 0, 0);
            }
    };

    // ---- prologue: stage k-tiles 0,1 into buffers 0,1
#pragma unroll
    for (int s = 0; s < 6; ++s)
        gload_lds16((const char*)src + goffs[s], smem + w * 6144 + s * 1024);
#pragma unroll
    for (int s = 0; s < 6; ++s)
        gload_lds16((const char*)src + goffs[s] + KS, smem + 49152 + w * 6144 + s * 1024);

    // ---- main loop: counted vmcnt(6) (per-wave counters) + raw barrier
    for (int kt = 0; kt < NTH - 1; ++kt) {
        asm volatile("s_waitcnt vmcnt(6)" ::: "memory");
        __builtin_amdgcn_s_barrier();
        if (kt + 2 < NTH) {
            char* dst = smem + ((kt + 2) % 3) * 49152 + w * 6144;
            const int kbyte = (kt + 2) * KS;
#pragma unroll
            for (int s = 0; s < 6; ++s)
                gload_lds16((const char*)src + goffs[s] + kbyte, dst + s * 1024);
        }
        compute(smem + (kt % 3) * 49152);
    }
    asm volatile("s_waitcnt vmcnt(0)" ::: "memory");
    __builtin_amdgcn_s_barrier();
    compute(smem + ((NTH - 1) % 3) * 49152);   // buffer 2; bufs 0,1 now free

    // ---- dequant to f32 (accH/accX die here; frees VGPRs for epilogue)
    const float sq = __uint_as_float(*amaxu) / 32639.0f;
    const float c1 = sq * sq * 65536.0f;
    const float c2 = sq * sq * 256.0f;
    f32x4 af[3][3];
#pragma unroll
    for (int m = 0; m < 3; ++m)
#pragma unroll
        for (int n = 0; n < 3; ++n)
#pragma unroll
            for (int r = 0; r < 4; ++r)
                af[m][n][r] = c1 * (float)accH[m][n][r] + c2 * (float)accX[m][n][r];

    // ---- a2 exchange (kh=1 -> LDS buf1) + QI/RJ staging (-> buf0)
    if (kh == 1) {
        char* pbase = smem + 49152 + sub * 9216 + lane * 144;
#pragma unroll
        for (int m = 0; m < 3; ++m)
#pragma unroll
            for (int n = 0; n < 3; ++n)
                *(f32x4*)(pbase + (m * 3 + n) * 16) = af[m][n];
    }
    if (w < 4) {        // QI: 96 rows x 128 B -> smem[0..12288)
#pragma unroll
        for (int sl = 0; sl < 3; ++sl) {
            int base = (w * 3 + sl) * 64;
            int idx  = base + lane;
            int c    = idx / 96;
            int row  = idx - c * 96;
            gload_lds16(QIh + (size_t)(i0 + row) * 64 + c * 8, smem + base * 16);
        }
    } else {            // RJ -> smem[12288..24576)
#pragma unroll
        for (int sl = 0; sl < 3; ++sl) {
            int base = ((w - 4) * 3 + sl) * 64;
            int idx  = base + lane;
            int c    = idx / 96;
            int row  = idx - c * 96;
            gload_lds16(RJh + (size_t)(j0 + row) * 64 + c * 8, smem + 12288 + base * 16);
        }
    }

    // epilogue geometry + early A loads (kh=0 only; latency hides under sync)
    const int crow = (lane >> 4) * 4;
    const int ccol = lane & 15;
    int il[3], jl[3];
#pragma unroll
    for (int m = 0; m < 3; ++m) il[m] = wr * 48 + m * 16 + crow;
#pragma unroll
    for (int n = 0; n < 3; ++n) jl[n] = wc * 48 + n * 16 + ccol;

    float av[3][3][4];
    if (kh == 0) {
#pragma unroll
        for (int m = 0; m < 3; ++m)
#pragma unroll
            for (int n = 0; n < 3; ++n)
#pragma unroll
                for (int r = 0; r < 4; ++r)
                    av[m][n][r] = A[(size_t)(i0 + il[m] + r) * NN + j0 + jl[n]];
    }

    __syncthreads();    // drains vmcnt (QI/RJ, A) + lgkm (a2 ds_writes)

    if (kh == 1) return;

    // ---- add partner half's a2
    {
        const char* pbase = smem + 49152 + sub * 9216 + lane * 144;
#pragma unroll
        for (int m = 0; m < 3; ++m)
#pragma unroll
            for (int n = 0; n < 3; ++n)
                af[m][n] += *(const f32x4*)(pbase + (m * 3 + n) * 16);
    }

    // ---- conv epilogue (f16 dot2, two-pass; r7/r13-verified)
    const char* QIl = smem;
    const char* RJl = smem + 12288;

    float c0 = b2[0];
#pragma unroll
    for (int f = 0; f < FDIM; ++f) c0 = fmaf(fmaxf(b1[f], 0.f), W2[f], c0);
    const float bb1 = b2[1], bb2 = b2[2];

    h16x2 w2h[32];
#pragma unroll
    for (int k = 0; k < 32; ++k) {
        h16x2 t; t.x = (_Float16)W2[32 + 2 * k]; t.y = (_Float16)W2[33 + 2 * k];
        w2h[k] = t;
    }

    float mm[3][3][4];
    // pass 1: chunks 0..3 (features 0..31, layer 1) -> m1, fold into av
#pragma unroll
    for (int m = 0; m < 3; ++m)
#pragma unroll
        for (int n = 0; n < 3; ++n)
#pragma unroll
            for (int r = 0; r < 4; ++r) mm[m][n][r] = 0.f;
#pragma unroll
    for (int c = 0; c < 4; ++c) {
        uint4 rv[3];
#pragma unroll
        for (int n = 0; n < 3; ++n)
            rv[n] = *(const uint4*)(RJl + (c * 96 + jl[n]) * 16);
        uint4 qv[3][4];
#pragma unroll
        for (int m = 0; m < 3; ++m)
#pragma unroll
            for (int r = 0; r < 4; ++r)
                qv[m][r] = *(const uint4*)(QIl + (c * 96 + il[m] + r) * 16);
#pragma unroll
        for (int m = 0; m < 3; ++m)
#pragma unroll
            for (int n = 0; n < 3; ++n) {
                const unsigned* ru = (const unsigned*)&rv[n];
#pragma unroll
                for (int r = 0; r < 4; ++r) {
                    const unsigned* qu = (const unsigned*)&qv[m][r];
                    float acc_f = mm[m][n][r];
#pragma unroll
                    for (int e = 0; e < 4; ++e) {
                        h16x2 q = __builtin_bit_cast(h16x2, qu[e]);
                        h16x2 j = __builtin_bit_cast(h16x2, ru[e]);
                        h16x2 h = q + j;
                        h16x2 z = {(_Float16)0, (_Float16)0};
                        h = __builtin_elementwise_max(h, z);
                        acc_f = __builtin_amdgcn_fdot2(h, w2h[c * 4 + e], acc_f, false);
                    }
                    mm[m][n][r] = acc_f;
                }
            }
    }
#pragma unroll
    for (int m = 0; m < 3; ++m)
#pragma unroll
        for (int n = 0; n < 3; ++n)
#pragma unroll
            for (int r = 0; r < 4; ++r)
                av[m][n][r] *= (mm[m][n][r] + bb1);

    // pass 2: chunks 4..7 (features 32..63, layer 2) -> m2
#pragma unroll
    for (int m = 0; m < 3; ++m)
#pragma unroll
        for (int n = 0; n < 3; ++n)
#pragma unroll
            for (int r = 0; r < 4; ++r) mm[m][n][r] = 0.f;
#pragma unroll
    for (int c = 4; c < 8; ++c) {
        uint4 rv[3];
#pragma unroll
        for (int n = 0; n < 3; ++n)
            rv[n] = *(const uint4*)(RJl + (c * 96 + jl[n]) * 16);
        uint4 qv[3][4];
#pragma unroll
        for (int m = 0; m < 3; ++m)
#pragma unroll
            for (int r = 0; r < 4; ++r)
                qv[m][r] = *(const uint4*)(QIl + (c * 96 + il[m] + r) * 16);
#pragma unroll
        for (int m = 0; m < 3; ++m)
#pragma unroll
            for (int n = 0; n < 3; ++n) {
                const unsigned* ru = (const unsigned*)&rv[n];
#pragma unroll
                for (int r = 0; r < 4; ++r) {
                    const unsigned* qu = (const unsigned*)&qv[m][r];
                    float acc_f = mm[m][n][r];
#pragma unroll
                    for (int e = 0; e < 4; ++e) {
                        h16x2 q = __builtin_bit_cast(h16x2, qu[e]);
                        h16x2 j = __builtin_bit_cast(h16x2, ru[e]);
                        h16x2 h = q + j;
                        h16x2 z = {(_Float16)0, (_Float16)0};
                        h = __builtin_elementwise_max(h, z);
                        acc_f = __builtin_amdgcn_fdot2(h, w2h[c * 4 + e], acc_f, false);
                    }
                    mm[m][n][r] = acc_f;
                }
            }
    }

    // final: out = A*(m1+bb1) + A2*(m2+bb2) + diag(c0)
#pragma unroll
    for (int m = 0; m < 3; ++m)
#pragma unroll
        for (int n = 0; n < 3; ++n)
#pragma unroll
            for (int r = 0; r < 4; ++r) {
                float v = av[m][n][r] + af[m][n][r] * (mm[m][n][r] + bb2);
                int gi = i0 + il[m] + r;
                int gj = j0 + jl[n];
                if (gi == gj) v += c0;
                out[(size_t)gi * NN + gj] = v;
            }
}

// ---------------------------------------------------------------------------
extern "C" void kernel_launch(void* const* d_in, const int* in_sizes, int n_in,
                              void* d_out, int out_size, void* d_ws, size_t ws_size,
                              hipStream_t stream) {
    const float* A  = (const float*)d_in[0];   // [NN,NN] A_norm (symmetric)
    const float* P  = (const float*)d_in[1];   // [NN,32]
    const float* W1 = (const float*)d_in[2];   // [3,32,32]
    const float* b1 = (const float*)d_in[3];   // [3,32]
    const float* W2 = (const float*)d_in[4];   // [3,32,1]
    const float* b2 = (const float*)d_in[5];   // [3,1]
    float* out = (float*)d_out;

    unsigned char* qH = (unsigned char*)d_ws;                    // NN*NN i8
    unsigned char* qL = qH + (size_t)NN * NN;                    // NN*NN i8
    _Float16* QIh = (_Float16*)(qL + (size_t)NN * NN);           // NN*64 f16
    _Float16* RJh = QIh + (size_t)NN * 64;                       // NN*64 f16
    unsigned* amax = (unsigned*)(RJh + (size_t)NN * 64);         // 1 u32

    hipMemsetAsync(amax, 0, 4, stream);
    gud_absmax<<<dim3(256), 256, 0, stream>>>(A, amax);
    gud_quantprep<<<dim3(NN * NN / 1024 + NN * 64 / 256), 256, 0, stream>>>(
        A, amax, qH, qL, P, W1, b1, QIh, RJh);
    gud_fused<<<dim3((NN / TG) * (NN / TG)), 512, 0, stream>>>(
        qH, qL, amax, A, QIh, RJh, b1, W2, b2, out);
}